// Round 10
// baseline (358.053 us; speedup 1.0000x reference)
//
#include <hip/hip_runtime.h>
#include <hip/hip_bf16.h>
#include <cstdint>

typedef __bf16 bf16_t;
typedef __bf16 bf16x8 __attribute__((ext_vector_type(8)));
typedef float  f32x4  __attribute__((ext_vector_type(4)));

#define MFMA16(a, b, c) __builtin_amdgcn_mfma_f32_16x16x32_bf16((a), (b), (c), 0, 0, 0)

constexpr int BB = 8, CC = 384, NHH = 6, TT = 1024;

union U8 { uint4 u; bf16_t h[8]; };
union U2 { unsigned int u; bf16_t h[2]; };

// ---------------------------------------------------------------------------
// K0: normalize all inputs to canonical bf16 (inputs fp32; probe kept).
// ---------------------------------------------------------------------------
struct CastArgs {
    const void* src[9];
    bf16_t*     dst[9];
    int         n[9];
};

__global__ __launch_bounds__(256) void cast_kernel(CastArgs a)
{
    const bool isbf = (((const unsigned short*)a.src[5])[0] == 0x3F80u);
    const int ai = blockIdx.y;
    const int n  = a.n[ai];
    bf16_t* dst  = a.dst[ai];
    const int t0     = (blockIdx.x * 256 + threadIdx.x) * 8;
    const int stride = gridDim.x * 256 * 8;
    if (isbf) {
        const bf16_t* s = (const bf16_t*)a.src[ai];
        for (int idx = t0; idx < n; idx += stride) {
            if (idx + 8 <= n) *(uint4*)(dst + idx) = *(const uint4*)(s + idx);
            else for (int j = 0; idx + j < n; ++j) dst[idx + j] = s[idx + j];
        }
    } else {
        const float* s = (const float*)a.src[ai];
        for (int idx = t0; idx < n; idx += stride) {
            if (idx + 8 <= n) {
                f32x4 v0 = *(const f32x4*)(s + idx);
                f32x4 v1 = *(const f32x4*)(s + idx + 4);
                U8 o;
                #pragma unroll
                for (int j = 0; j < 4; ++j) { o.h[j] = (bf16_t)v0[j]; o.h[4 + j] = (bf16_t)v1[j]; }
                *(uint4*)(dst + idx) = o.u;
            } else for (int j = 0; idx + j < n; ++j) dst[idx + j] = (bf16_t)s[idx + j];
        }
    }
}

// ---------------------------------------------------------------------------
// K1: QKV projection + fused V row-sums.
//  q/k branch: A=W (D rows=o, regs span 4 consecutive o) -> b64 packed [t][o].
//  v branch: A=xT (regs span t) -> b64 packed vm[o][t]; epilogue reduces
//  fp32 accs over t and atomicAdds per-o row sums into vrs (pre-zeroed).
// ---------------------------------------------------------------------------
__global__ __launch_bounds__(256) void qkv_kernel(
    const bf16_t* __restrict__ x,
    const bf16_t* __restrict__ Wq,
    const bf16_t* __restrict__ Wk,
    const bf16_t* __restrict__ Wv,
    bf16_t* __restrict__ qT,
    bf16_t* __restrict__ kT,
    bf16_t* __restrict__ vm,
    float* __restrict__ vrs)
{
    const int og = blockIdx.x;        // 0,1:q  2,3:k  4,5:v
    const int tt = blockIdx.y;
    const int b  = blockIdx.z;
    const int t0 = tt * 64;
    const int tid  = threadIdx.x;
    const int lane = tid & 63;
    const int wid  = tid >> 6;
    const int quad = lane >> 4;
    const int l16  = lane & 15;

    __shared__ __align__(16) bf16_t xT[64][CC + 8];

    {
        const bf16_t* xb = x + (size_t)b * CC * TT;
        const int tq = tid & 7;
        const int cp = tid >> 3;
        #pragma unroll
        for (int pass = 0; pass < 6; ++pass) {
            const int c = (pass * 32 + cp) * 2;
            U8 r0, r1;
            r0.u = *(const uint4*)(xb + (size_t)c * TT + t0 + tq * 8);
            r1.u = *(const uint4*)(xb + (size_t)(c + 1) * TT + t0 + tq * 8);
            #pragma unroll
            for (int j = 0; j < 8; ++j) {
                U2 p; p.h[0] = r0.h[j]; p.h[1] = r1.h[j];
                *(unsigned int*)&xT[tq * 8 + j][c] = p.u;
            }
        }
    }
    __syncthreads();

    const bf16_t* W = (og < 2) ? Wq : (og < 4) ? Wk : Wv;
    const int obase = (og & 1) * 192 + wid * 48;

    if (og < 4) {
        f32x4 acc[3][4];
        const f32x4 zero = {0.f, 0.f, 0.f, 0.f};
        #pragma unroll
        for (int mi = 0; mi < 3; ++mi)
            #pragma unroll
            for (int ni = 0; ni < 4; ++ni) acc[mi][ni] = zero;

        for (int k0 = 0; k0 < CC; k0 += 32) {
            bf16x8 afr[3];
            #pragma unroll
            for (int mi = 0; mi < 3; ++mi)
                afr[mi] = *(const bf16x8*)(W + (size_t)(obase + mi * 16 + l16) * CC + k0 + quad * 8);
            #pragma unroll
            for (int ni = 0; ni < 4; ++ni) {
                bf16x8 bfr = *(const bf16x8*)&xT[ni * 16 + l16][k0 + quad * 8];
                #pragma unroll
                for (int mi = 0; mi < 3; ++mi)
                    acc[mi][ni] = MFMA16(afr[mi], bfr, acc[mi][ni]);
            }
        }

        bf16_t* dst = (og < 2) ? qT : kT;
        #pragma unroll
        for (int mi = 0; mi < 3; ++mi)
            #pragma unroll
            for (int ni = 0; ni < 4; ++ni) {
                const int o0 = obase + mi * 16 + quad * 4;
                const int tl = t0 + ni * 16 + l16;
                U2 lo2, hi2;
                lo2.h[0] = (bf16_t)acc[mi][ni][0]; lo2.h[1] = (bf16_t)acc[mi][ni][1];
                hi2.h[0] = (bf16_t)acc[mi][ni][2]; hi2.h[1] = (bf16_t)acc[mi][ni][3];
                uint2 pk; pk.x = lo2.u; pk.y = hi2.u;
                *(uint2*)(dst + ((size_t)b * TT + tl) * CC + o0) = pk;
            }
    } else {
        f32x4 acc[4][3];
        const f32x4 zero = {0.f, 0.f, 0.f, 0.f};
        #pragma unroll
        for (int mi = 0; mi < 4; ++mi)
            #pragma unroll
            for (int ni = 0; ni < 3; ++ni) acc[mi][ni] = zero;

        for (int k0 = 0; k0 < CC; k0 += 32) {
            bf16x8 bfr[3];
            #pragma unroll
            for (int ni = 0; ni < 3; ++ni)
                bfr[ni] = *(const bf16x8*)(W + (size_t)(obase + ni * 16 + l16) * CC + k0 + quad * 8);
            #pragma unroll
            for (int mi = 0; mi < 4; ++mi) {
                bf16x8 afr = *(const bf16x8*)&xT[mi * 16 + l16][k0 + quad * 8];
                #pragma unroll
                for (int ni = 0; ni < 3; ++ni)
                    acc[mi][ni] = MFMA16(afr, bfr[ni], acc[mi][ni]);
            }
        }

        #pragma unroll
        for (int ni = 0; ni < 3; ++ni) {
            const int ol = obase + ni * 16 + l16;
            float s = 0.f;
            #pragma unroll
            for (int mi = 0; mi < 4; ++mi) {
                const int tl0 = mi * 16 + quad * 4;
                U2 lo2, hi2;
                lo2.h[0] = (bf16_t)acc[mi][ni][0]; lo2.h[1] = (bf16_t)acc[mi][ni][1];
                hi2.h[0] = (bf16_t)acc[mi][ni][2]; hi2.h[1] = (bf16_t)acc[mi][ni][3];
                uint2 pk; pk.x = lo2.u; pk.y = hi2.u;
                *(uint2*)(vm + ((size_t)b * CC + ol) * TT + t0 + tl0) = pk;
                s += acc[mi][ni][0] + acc[mi][ni][1] + acc[mi][ni][2] + acc[mi][ni][3];
            }
            // fp32 row-sum over this block's 64 t (quad butterfly), 1 atomic/o
            s += __shfl_xor(s, 16, 64);
            s += __shfl_xor(s, 32, 64);
            if (quad == 0) atomicAdd(&vrs[b * CC + ol], s);
        }
    }
}

// ---------------------------------------------------------------------------
// K2: fused attention v2.  Block = (b, g, 64 q-rows); 8 t-tiles of 128.
//  - smix folded into Bt staging (per-BK-chunk uniform scalar).
//  - register prefetch: pA/pB for next kk, pV for the tile -> global latency
//    overlaps MFMA instead of draining at the barrier.
//  - PV single-pass: Ps 64x128 (full t-tile) + Vt 64x128 staged once,
//    16-MFMA burst.  14 barriers/tile (was 17).  LDS 32.8 KB.
// ---------------------------------------------------------------------------
__global__ __launch_bounds__(256, 3) void fused_attn(
    const bf16_t* __restrict__ qT,
    const bf16_t* __restrict__ kT,
    const bf16_t* __restrict__ vm,
    const bf16_t* __restrict__ head_w,
    float* __restrict__ Uhat,
    float* __restrict__ sumsq)
{
    const int L  = blockIdx.x;
    const int b  = L & 7;
    const int rr = L >> 3;
    const int qt = rr & 15;
    const int g  = rr >> 4;
    const int qbase = qt * 64;
    const int tid = threadIdx.x, lane = tid & 63, wid = tid >> 6;
    const int quad = lane >> 4, l16 = lane & 15;
    const int Msub = (wid & 1) * 64;       // score: t-half
    const int Nsub = (wid >> 1) * 32;      // score: q-half

    __shared__ __align__(16) bf16_t sm[16384];   // 32 KB union
    bf16_t* At = sm;              // [128][64] swizzled (score phase)
    bf16_t* Bt = sm + 8192;       // [64][64]           (score phase)
    bf16_t* Ps = sm;              // [64 q][128 t]      (PV phase)
    bf16_t* Vt = sm + 8192;       // [64 d][128 t]      (PV phase)
    __shared__ float lred[4][2][16], l2red[4][2][16];
    __shared__ float lrowS[64];

    float smix6[6];
    #pragma unroll
    for (int h = 0; h < 6; ++h) smix6[h] = 0.125f * (float)head_w[g * 6 + h];

    const bf16_t* kTb = kT + (size_t)b * TT * CC;
    const bf16_t* Qb  = qT + ((size_t)b * TT + qbase) * CC;
    const bf16_t* Vb  = vm + ((size_t)b * CC + g * 64) * TT;

    // staging coordinates (fixed per thread)
    const int arow = tid >> 1, ach0 = (tid & 1) * 4;          // At: 4 chunks
    const int brow = tid >> 2, bch  = tid & 3;                // Bt: rows x2 its? (see loop)
    const int vrow = tid >> 2, vch0 = (tid & 3) * 4;          // Vt: 4 chunks

    float lacc[2] = {0.f, 0.f}, l2acc[2] = {0.f, 0.f};
    f32x4 U[4];
    const f32x4 zero = {0.f, 0.f, 0.f, 0.f};
    #pragma unroll
    for (int n2 = 0; n2 < 4; ++n2) U[n2] = zero;

    uint4 pA[4], pB[2], pV[4];
    auto loadAB = [&](int ttp, int kkp) {
        #pragma unroll
        for (int it = 0; it < 4; ++it) {
            const int id = it * 256 + tid;
            const int row = id >> 3, ch = id & 7;
            pA[it] = *(const uint4*)(kTb + (size_t)(ttp * 128 + row) * CC + kkp * 64 + ch * 8);
        }
        #pragma unroll
        for (int it = 0; it < 2; ++it) {
            const int id = it * 256 + tid;
            const int row = id >> 3, ch = id & 7;
            pB[it] = *(const uint4*)(Qb + (size_t)row * CC + kkp * 64 + ch * 8);
        }
    };

    loadAB(0, 0);

    for (int tt = 0; tt < 8; ++tt) {
        // prefetch V for this tile (consumed after the kk loop)
        #pragma unroll
        for (int it = 0; it < 4; ++it) {
            const int id = it * 256 + tid;
            const int row = id >> 4, ch = id & 15;
            pV[it] = *(const uint4*)(Vb + (size_t)row * TT + tt * 128 + ch * 8);
        }

        f32x4 S[4][2];
        #pragma unroll
        for (int mi = 0; mi < 4; ++mi)
            #pragma unroll
            for (int ni = 0; ni < 2; ++ni) S[mi][ni] = zero;

        for (int kk = 0; kk < 6; ++kk) {
            __syncthreads();   // union region free (prev MFMA / prev-tile PV done)
            #pragma unroll
            for (int it = 0; it < 4; ++it) {
                const int id = it * 256 + tid;
                const int row = id >> 3, ch = id & 7;
                *(uint4*)&At[row * 64 + ((ch ^ (row & 7)) * 8)] = pA[it];
            }
            const float m = smix6[kk];
            #pragma unroll
            for (int it = 0; it < 2; ++it) {
                const int id = it * 256 + tid;
                const int row = id >> 3, ch = id & 7;
                U8 v; v.u = pB[it];
                U8 o;
                #pragma unroll
                for (int j = 0; j < 8; ++j) o.h[j] = (bf16_t)((float)v.h[j] * m);
                *(uint4*)&Bt[row * 64 + ((ch ^ (row & 7)) * 8)] = o.u;
            }
            // issue next prefetch (overlaps this kk's MFMAs)
            {
                int nkk = kk + 1, ntt = tt;
                if (nkk == 6) { nkk = 0; ntt = tt + 1; }
                if (ntt < 8) loadAB(ntt, nkk);
            }
            __syncthreads();
            #pragma unroll
            for (int k2 = 0; k2 < 2; ++k2) {
                const int sw = ((k2 * 4 + quad) ^ (l16 & 7)) * 8;
                bf16x8 a[4], bq[2];
                #pragma unroll
                for (int mi = 0; mi < 4; ++mi)
                    a[mi] = *(const bf16x8*)&At[(Msub + mi * 16 + l16) * 64 + sw];
                #pragma unroll
                for (int ni = 0; ni < 2; ++ni)
                    bq[ni] = *(const bf16x8*)&Bt[(Nsub + ni * 16 + l16) * 64 + sw];
                #pragma unroll
                for (int mi = 0; mi < 4; ++mi)
                    #pragma unroll
                    for (int ni = 0; ni < 2; ++ni)
                        S[mi][ni] = MFMA16(a[mi], bq[ni], S[mi][ni]);
            }
        }

        // exp in regs + row partials
        #pragma unroll
        for (int mi = 0; mi < 4; ++mi)
            #pragma unroll
            for (int ni = 0; ni < 2; ++ni)
                #pragma unroll
                for (int r = 0; r < 4; ++r) {
                    const float p = __expf(fminf(S[mi][ni][r], 60.0f));
                    S[mi][ni][r] = p;
                    lacc[ni]  += p;
                    l2acc[ni] += p * p;
                }

        __syncthreads();   // At/Bt reads done -> Ps/Vt writable

        // stage Vt (from prefetch regs)
        #pragma unroll
        for (int it = 0; it < 4; ++it) {
            const int id = it * 256 + tid;
            const int row = id >> 4, ch = id & 15;
            *(uint4*)&Vt[row * 128 + ((((ch & 7) ^ (row & 7)) | (ch & 8)) * 8)] = pV[it];
        }
        // write full-width Ps (q rows x 128 t, swizzled 8-chunks)
        #pragma unroll
        for (int mi = 0; mi < 4; ++mi) {
            const int tc = (Msub >> 3) + mi * 2 + (quad >> 1);
            const int off = (quad & 1) * 4;
            #pragma unroll
            for (int ni = 0; ni < 2; ++ni) {
                const int q = Nsub + ni * 16 + l16;
                U2 lo2, hi2;
                lo2.h[0] = (bf16_t)S[mi][ni][0]; lo2.h[1] = (bf16_t)S[mi][ni][1];
                hi2.h[0] = (bf16_t)S[mi][ni][2]; hi2.h[1] = (bf16_t)S[mi][ni][3];
                uint2 pk; pk.x = lo2.u; pk.y = hi2.u;
                *(uint2*)&Ps[q * 128 + ((((tc & 7) ^ (q & 7)) | (tc & 8)) * 8) + off] = pk;
            }
        }
        __syncthreads();   // Ps + Vt ready

        // PV burst: wave owns q in [wid*16, +16), all 64 d, K = 128 t
        const int qa = wid * 16 + l16;
        #pragma unroll
        for (int k2 = 0; k2 < 4; ++k2) {
            const int tc = k2 * 4 + quad;
            bf16x8 ap = *(const bf16x8*)&Ps[qa * 128 + ((((tc & 7) ^ (qa & 7)) | (tc & 8)) * 8)];
            #pragma unroll
            for (int n2 = 0; n2 < 4; ++n2) {
                const int d = n2 * 16 + l16;
                bf16x8 bv = *(const bf16x8*)&Vt[d * 128 + ((((tc & 7) ^ (d & 7)) | (tc & 8)) * 8)];
                U[n2] = MFMA16(ap, bv, U[n2]);
            }
        }
        // next tile's first __syncthreads() protects Ps/Vt overwrite
    }

    // ---- row stats
    #pragma unroll
    for (int ni = 0; ni < 2; ++ni) {
        float l = lacc[ni], l2 = l2acc[ni];
        l  += __shfl_xor(l, 16, 64);  l  += __shfl_xor(l, 32, 64);
        l2 += __shfl_xor(l2, 16, 64); l2 += __shfl_xor(l2, 32, 64);
        if (quad == 0) { lred[wid][ni][l16] = l; l2red[wid][ni][l16] = l2; }
    }
    __syncthreads();
    if (tid < 64) {
        const int q = tid;
        const int w0 = (q >> 5) * 2, ni = (q >> 4) & 1, lo = q & 15;
        const float l  = lred[w0][ni][lo]  + lred[w0 + 1][ni][lo];
        const float l2 = l2red[w0][ni][lo] + l2red[w0 + 1][ni][lo];
        lrowS[q] = l;
        float c = l2 / (l * l);
        #pragma unroll
        for (int off = 1; off < 64; off <<= 1) c += __shfl_xor(c, off, 64);
        if (tid == 0) atomicAdd(&sumsq[b * NHH + g], c);
    }
    __syncthreads();

    // ---- Uhat = U / l  (fp32, flat [b][g][q][d])
    float* Ub = Uhat + ((size_t)(b * NHH + g) * TT + qbase) * 64;
    #pragma unroll
    for (int r = 0; r < 4; ++r) {
        const int ql = wid * 16 + quad * 4 + r;
        const float invl = 1.0f / lrowS[ql];
        #pragma unroll
        for (int n2 = 0; n2 < 4; ++n2)
            Ub[(size_t)ql * 64 + n2 * 16 + l16] = U[n2][r] * invl;
    }
}

// ---------------------------------------------------------------------------
// K3: projection + fused InstanceNorm affine + bias + transpose.
// ---------------------------------------------------------------------------
__global__ __launch_bounds__(256) void proj_kernel(
    const float* __restrict__ Uhat,
    const float* __restrict__ vrs,
    const float* __restrict__ sumsq,
    const bf16_t* __restrict__ gamma,
    const bf16_t* __restrict__ beta,
    const bf16_t* __restrict__ projW,
    const bf16_t* __restrict__ projb,
    float* __restrict__ out)
{
    const int ts = blockIdx.x;
    const int b  = blockIdx.y;
    const int t0 = ts * 32;
    const int tid = threadIdx.x, lane = tid & 63, wid = tid >> 6;
    const int quad = lane >> 4, l16 = lane & 15;

    __shared__ float Ac[6], Cc[6], pb[CC];
    if (tid < 6) {
        const float ss  = sumsq[b * NHH + tid];
        const float var = fmaxf(ss - 1.0f, 0.0f) * (1.0f / 1048576.0f);
        const float a   = (float)gamma[tid] * rsqrtf(var + 1e-5f);
        Ac[tid] = a;
        Cc[tid] = (float)beta[tid] - a * (1.0f / 1024.0f);
    }
    for (int i = tid; i < CC; i += 256) pb[i] = (float)projb[i];
    __syncthreads();

    f32x4 acc[6][2];
    const f32x4 zero = {0.f, 0.f, 0.f, 0.f};
    #pragma unroll
    for (int mi = 0; mi < 6; ++mi)
        #pragma unroll
        for (int ni = 0; ni < 2; ++ni) acc[mi][ni] = zero;

    const float* Ub = Uhat + (size_t)b * TT * CC;
    for (int k0 = 0; k0 < CC; k0 += 32) {
        bf16x8 bfr[2];
        #pragma unroll
        for (int ni = 0; ni < 2; ++ni) {
            const int tl = t0 + ni * 16 + l16;
            const int baseoff = tl * CC + k0 + quad * 8;
            f32x4 u0 = *(const f32x4*)(Ub + baseoff);
            f32x4 u1 = *(const f32x4*)(Ub + baseoff + 4);
            U8 z;
            #pragma unroll
            for (int j = 0; j < 8; ++j) {
                const int off = baseoff + j;
                const int h = off >> 16;
                const int d = off & 63;
                const float uv = (j < 4) ? u0[j] : u1[j - 4];
                z.h[j] = (bf16_t)(Ac[h] * uv + Cc[h] * vrs[b * CC + h * 64 + d]);
            }
            bfr[ni] = *(const bf16x8*)&z;
        }
        #pragma unroll
        for (int mi = 0; mi < 6; ++mi) {
            const int o = wid * 96 + mi * 16 + l16;
            bf16x8 afr = *(const bf16x8*)(projW + (size_t)o * CC + k0 + quad * 8);
            #pragma unroll
            for (int ni = 0; ni < 2; ++ni)
                acc[mi][ni] = MFMA16(afr, bfr[ni], acc[mi][ni]);
        }
    }

    #pragma unroll
    for (int mi = 0; mi < 6; ++mi)
        #pragma unroll
        for (int ni = 0; ni < 2; ++ni)
            #pragma unroll
            for (int r = 0; r < 4; ++r) {
                const int o  = wid * 96 + mi * 16 + quad * 4 + r;
                const int tl = t0 + ni * 16 + l16;
                out[((size_t)b * CC + o) * TT + tl] = acc[mi][ni][r] + pb[o];
            }
}

// ---------------------------------------------------------------------------
extern "C" void kernel_launch(void* const* d_in, const int* in_sizes, int n_in,
                              void* d_out, int out_size, void* d_ws, size_t ws_size,
                              hipStream_t stream)
{
    float* outp = (float*)d_out;
    char* ws = (char*)d_ws;

    size_t off = 0;
    auto alloc = [&](size_t bytes) {
        void* p = ws + off;
        off += (bytes + 255) & ~(size_t)255;
        return p;
    };

    const size_t szQ = (size_t)BB * TT * CC * sizeof(bf16_t);   // 6 MB

    bf16_t* cx  = (bf16_t*)alloc(szQ);
    bf16_t* cWq = (bf16_t*)alloc((size_t)CC * CC * 2);
    bf16_t* cWk = (bf16_t*)alloc((size_t)CC * CC * 2);
    bf16_t* cWv = (bf16_t*)alloc((size_t)CC * CC * 2);
    bf16_t* cPW = (bf16_t*)alloc((size_t)CC * CC * 2);
    bf16_t* chw = (bf16_t*)alloc(64 * 2);
    bf16_t* cg  = (bf16_t*)alloc(64 * 2);
    bf16_t* cb  = (bf16_t*)alloc(64 * 2);
    bf16_t* cpb = (bf16_t*)alloc(CC * 2);
    bf16_t* qT  = (bf16_t*)alloc(szQ);
    bf16_t* kT  = (bf16_t*)alloc(szQ);
    bf16_t* vm  = (bf16_t*)alloc(szQ);
    float*  Uh  = (float*)alloc((size_t)BB * NHH * TT * 64 * 4);   // 12.6 MB
    float*  vr  = (float*)alloc(BB * CC * 4);                      // 12 KB
    float*  sq  = (float*)alloc(48 * 4);                           // adjacent to vr

    CastArgs ca;
    bf16_t* dsts[9] = {cx, cWq, cWk, cWv, chw, cg, cb, cPW, cpb};
    for (int i = 0; i < 9; ++i) {
        ca.src[i] = d_in[i];
        ca.dst[i] = dsts[i];
        ca.n[i]   = in_sizes[i];
    }

    hipMemsetAsync(vr, 0, BB * CC * 4 + 256, stream);   // vr + sq (contiguous)
    cast_kernel<<<dim3(192, 9), 256, 0, stream>>>(ca);
    qkv_kernel<<<dim3(6, 16, 8), 256, 0, stream>>>(cx, cWq, cWk, cWv, qT, kT, vm, vr);
    fused_attn<<<768, 256, 0, stream>>>(qT, kT, vm, chw, Uh, sq);
    proj_kernel<<<dim3(32, 8), 256, 0, stream>>>(Uh, vr, sq, cg, cb, cPW, cpb, outp);
}